// Round 1
// baseline (348.991 us; speedup 1.0000x reference)
//
#include <hip/hip_runtime.h>

typedef unsigned short u16;
typedef float f32x4 __attribute__((ext_vector_type(4)));
typedef __bf16 bf16x8 __attribute__((ext_vector_type(8)));

#define MFMA16(a, b, c) __builtin_amdgcn_mfma_f32_16x16x32_bf16((a), (b), (c), 0, 0, 0)

#define B_ 8
#define H_ 8
#define S_ 1024
static constexpr float INV_SCALE = 0.35355339059327373f; // 1/sqrt(B)

__device__ __forceinline__ u16 f2bf(float f) {
  unsigned u = __float_as_uint(f);
  return (u16)((u + 0x7fffu + ((u >> 16) & 1u)) >> 16);
}
__device__ __forceinline__ float bf2f(u16 h) {
  return __uint_as_float(((unsigned)h) << 16);
}
// async global->LDS, 16B per lane. LDS dest = wave-uniform base + lane*16.
__device__ __forceinline__ void gload16(const void* g, void* l) {
  __builtin_amdgcn_global_load_lds((__attribute__((address_space(1))) const void*)g,
                                   (__attribute__((address_space(3))) void*)l, 16, 0, 0);
}

// ---------------- converts ----------------
__global__ void __launch_bounds__(256) conv3(const float* __restrict__ q, const float* __restrict__ k,
                                             const float* __restrict__ v,
                                             u16* __restrict__ dq, u16* __restrict__ dk, u16* __restrict__ dv) {
  size_t i4 = (size_t)blockIdx.x * 256 + threadIdx.x;   // float4 index; 3*1048576 total
  int tsel = (int)(i4 >> 20);
  size_t off = (i4 & 1048575) << 2;
  const float* s = tsel == 0 ? q : (tsel == 1 ? k : v);
  u16* d = tsel == 0 ? dq : (tsel == 1 ? dk : dv);
  float4 f = *(const float4*)(s + off);
  uint2 o; u16* po = (u16*)&o;
  po[0] = f2bf(f.x); po[1] = f2bf(f.y); po[2] = f2bf(f.z); po[3] = f2bf(f.w);
  *(uint2*)(d + off) = o;
}

__global__ void __launch_bounds__(256) conv5(const float* __restrict__ s0, const float* __restrict__ s1,
                                             const float* __restrict__ s2, const float* __restrict__ s3,
                                             const float* __restrict__ s4,
                                             u16* __restrict__ d0, u16* __restrict__ d1, u16* __restrict__ d2,
                                             u16* __restrict__ d3, u16* __restrict__ d4) {
  size_t i = ((size_t)blockIdx.x * 256 + threadIdx.x) << 2;
  if (i >= 1050688) return; // 4*262144 + 33*64
  const float* s; u16* d; size_t off;
  if (i < 262144)       { s = s0; d = d0; off = i; }
  else if (i < 524288)  { s = s1; d = d1; off = i - 262144; }
  else if (i < 786432)  { s = s2; d = d2; off = i - 524288; }
  else if (i < 1048576) { s = s3; d = d3; off = i - 786432; }
  else                  { s = s4; d = d4; off = i - 1048576; }
  float4 f = *(const float4*)(s + off);
  uint2 o; u16* po = (u16*)&o;
  po[0] = f2bf(f.x); po[1] = f2bf(f.y); po[2] = f2bf(f.z); po[3] = f2bf(f.w);
  *(uint2*)(d + off) = o;
}

// ---------------- GEMM: C[M=8192][N=512] = A(bf16) @ W(bf16)^T + bias ----------------
// MODE 0: write bf16 head-split [B,H,S,64]; MODE 1: write fp32 row-major [M][512].
template <int MODE>
__global__ void __launch_bounds__(256) gemm_bt(const u16* __restrict__ A, const u16* __restrict__ W,
                                               const float* __restrict__ bias, void* __restrict__ out) {
  __shared__ u16 As[128 * 64];
  __shared__ u16 Bs[128 * 64];
  const int tid = threadIdx.x, lane = tid & 63, wid = tid >> 6;
  const int c = lane & 15, g = lane >> 4;
  const int bm = blockIdx.x >> 2, bn = blockIdx.x & 3;
  const int m0 = bm << 7, n0 = bn << 7;
  const int wrow = (wid >> 1) << 6, wcol = (wid & 1) << 6;

  const f32x4 ZF = {0.f, 0.f, 0.f, 0.f};
  f32x4 acc[4][4];
#pragma unroll
  for (int i = 0; i < 4; ++i)
#pragma unroll
    for (int j = 0; j < 4; ++j) acc[i][j] = ZF;

  for (int kt = 0; kt < 512; kt += 64) {
    __syncthreads();
#pragma unroll
    for (int i = 0; i < 4; ++i) {
      int Lb = ((wid << 2) | i) << 10;
      int L = Lb + lane * 16;
      int row = L >> 7;                                 // 0..127
      int off = (L & 127) ^ ((row & 7) << 4);           // pre-swizzled source
      gload16((const char*)A + ((((size_t)(m0 + row)) << 9) + kt) * 2 + off, (char*)As + Lb);
      gload16((const char*)W + ((((size_t)(n0 + row)) << 9) + kt) * 2 + off, (char*)Bs + Lb);
    }
    __syncthreads();
#pragma unroll
    for (int kk = 0; kk < 2; ++kk) {
      bf16x8 af[4], bfr[4];
#pragma unroll
      for (int rt = 0; rt < 4; ++rt) {
        int row = wrow + (rt << 4) + c;
        af[rt] = *(const bf16x8*)((const char*)As + row * 128 + (((kk << 6) | (g << 4)) ^ ((row & 7) << 4)));
      }
#pragma unroll
      for (int ct = 0; ct < 4; ++ct) {
        int row = wcol + (ct << 4) + c;
        bfr[ct] = *(const bf16x8*)((const char*)Bs + row * 128 + (((kk << 6) | (g << 4)) ^ ((row & 7) << 4)));
      }
#pragma unroll
      for (int rt = 0; rt < 4; ++rt)
#pragma unroll
        for (int ct = 0; ct < 4; ++ct) acc[rt][ct] = MFMA16(af[rt], bfr[ct], acc[rt][ct]);
    }
  }

#pragma unroll
  for (int rt = 0; rt < 4; ++rt)
#pragma unroll
    for (int ct = 0; ct < 4; ++ct) {
      int n = n0 + wcol + (ct << 4) + c;
      float bv = bias[n];
#pragma unroll
      for (int r = 0; r < 4; ++r) {
        int m = m0 + wrow + (rt << 4) + (g << 2) + r;
        float v = acc[rt][ct][r] + bv;
        if (MODE == 0) {
          int b = m >> 10, s = m & 1023, h = n >> 6, d = n & 63;
          ((u16*)out)[(((((size_t)(b * H_ + h)) << 10) + s) << 6) + d] = f2bf(v);
        } else {
          ((float*)out)[(((size_t)m) << 9) + n] = v;
        }
      }
    }
}

// ---------------- V transpose: [BH, S, 64] -> [BH, 64, S] ----------------
__global__ void __launch_bounds__(256) transpose_v(const u16* __restrict__ Vh, u16* __restrict__ Vt) {
  __shared__ u16 tile[64 * 68];
  const int t = threadIdx.x;
  const int bh = blockIdx.x >> 4, st = blockIdx.x & 15;
  {
    int sl = t >> 2, cc = t & 3;
    const u16* src = Vh + ((((size_t)bh << 10) + (st << 6) + sl) << 6) + (cc << 4);
    const uint2* s2 = (const uint2*)src;
    uint2* d2 = (uint2*)((char*)tile + sl * 136 + (cc << 5));
    d2[0] = s2[0]; d2[1] = s2[1]; d2[2] = s2[2]; d2[3] = s2[3];
  }
  __syncthreads();
  {
    int d = t >> 2, sc = t & 3;
    uint4 o0, o1; u16* p0 = (u16*)&o0; u16* p1 = (u16*)&o1;
#pragma unroll
    for (int i = 0; i < 8; ++i) {
      p0[i] = tile[(sc * 16 + i) * 68 + d];
      p1[i] = tile[(sc * 16 + 8 + i) * 68 + d];
    }
    u16* dst = Vt + ((((size_t)bh << 6) + d) << 10) + (st << 6) + (sc << 4);
    *(uint4*)dst = o0;
    *(uint4*)(dst + 8) = o1;
  }
}

// ---------------- qrel[row][r] = Q[row,:] . rel_k[r,:]  (rows=65536, r<33) ----------------
__global__ void __launch_bounds__(256) qrel_gemm(const u16* __restrict__ Qh, const u16* __restrict__ relkb,
                                                 float* __restrict__ qrelB) {
  const int lane = threadIdx.x & 63, wid = threadIdx.x >> 6;
  const int c = lane & 15, g = lane >> 4;
  const size_t rbase = (((size_t)blockIdx.x << 2) + wid) << 4;
  bf16x8 qa[2];
#pragma unroll
  for (int kk = 0; kk < 2; ++kk)
    qa[kk] = *(const bf16x8*)(Qh + ((rbase + c) << 6) + (kk << 5) + (g << 3));
  const f32x4 ZF = {0.f, 0.f, 0.f, 0.f};
  f32x4 acc[3] = {ZF, ZF, ZF};
#pragma unroll
  for (int ct = 0; ct < 3; ++ct) {
    int r = ct * 16 + c; if (r > 32) r = 32;  // clamp: cols>32 discarded
#pragma unroll
    for (int kk = 0; kk < 2; ++kk) {
      bf16x8 bfr = *(const bf16x8*)(relkb + (r << 6) + (kk << 5) + (g << 3));
      acc[ct] = MFMA16(qa[kk], bfr, acc[ct]);
    }
  }
#pragma unroll
  for (int ct = 0; ct < 3; ++ct)
#pragma unroll
    for (int r = 0; r < 4; ++r) {
      int col = ct * 16 + c;
      if (col < 33) qrelB[(rbase + (g << 2) + r) * 33 + col] = acc[ct][r];
    }
}

// ---------------- flash attention with relative-K bias + low-bucket tracking ----------------
__global__ void __launch_bounds__(256) flash_kernel(const u16* __restrict__ Qh, const u16* __restrict__ Kh,
                                                    const u16* __restrict__ Vt, const float* __restrict__ qrel,
                                                    u16* __restrict__ Xout, float* __restrict__ Mg,
                                                    float* __restrict__ Lg, float* __restrict__ LOWg) {
  __shared__ u16 Ks[64 * 64];
  __shared__ u16 Vs[64 * 64];
  __shared__ u16 Ps[4 * 16 * 64];
  __shared__ float qrelS[64 * 33];

  const int tid = threadIdx.x, lane = tid & 63, wid = tid >> 6;
  const int c = lane & 15, g = lane >> 4;
  const int bh = blockIdx.x >> 4, qt = blockIdx.x & 15;
  const int qbase = qt << 6;
  const size_t rowbase = ((size_t)bh) << 10;

  for (int i = tid; i < 64 * 33; i += 256) qrelS[i] = qrel[(rowbase + qbase) * 33 + i];

  const int qrow = qbase + (wid << 4) + c;
  bf16x8 qa[2];
#pragma unroll
  for (int kk = 0; kk < 2; ++kk)
    qa[kk] = *(const bf16x8*)(Qh + ((rowbase + qrow) << 6) + (kk << 5) + (g << 3));

  const f32x4 ZF = {0.f, 0.f, 0.f, 0.f};
  f32x4 acc[4] = {ZF, ZF, ZF, ZF};
  float mreg[4], lreg[4], lowreg[4];
#pragma unroll
  for (int j = 0; j < 4; ++j) { mreg[j] = -1e30f; lreg[j] = 0.f; lowreg[j] = 0.f; }

  for (int kt = 0; kt < 16; ++kt) {
    const int k64 = kt << 6;
    __syncthreads();
#pragma unroll
    for (int i = 0; i < 2; ++i) {
      int Lb2 = ((wid << 1) | i) << 10;
      int L = Lb2 + lane * 16;
      int row = L >> 7;                           // 0..63
      int off = (L & 127) ^ ((row & 7) << 4);
      gload16((const char*)Kh + ((rowbase + k64 + row) << 7) + off, (char*)Ks + Lb2);
      gload16((const char*)Vt + ((((size_t)bh << 6) + row) << 11) + (k64 << 1) + off, (char*)Vs + Lb2);
    }
    __syncthreads();

    // QK^T: 16 q-rows x 64 k-cols per wave
    f32x4 sa[4];
#pragma unroll
    for (int t = 0; t < 4; ++t) {
      sa[t] = ZF;
#pragma unroll
      for (int kk = 0; kk < 2; ++kk) {
        int row = (t << 4) + c;
        bf16x8 bk = *(const bf16x8*)((const char*)Ks + row * 128 + (((kk << 6) | (g << 4)) ^ ((row & 7) << 4)));
        sa[t] = MFMA16(qa[kk], bk, sa[t]);
      }
    }

    float p[4][4], corr[4];
#pragma unroll
    for (int j = 0; j < 4; ++j) {
      const int qloc = (wid << 4) + (g << 2) + j;
      const int qg = qbase + qloc;
      float s0[4];
#pragma unroll
      for (int t = 0; t < 4; ++t) {
        int kg = k64 + (t << 4) + c;
        int dlt = kg - qg;
        int idx = (dlt < -16 ? -16 : (dlt > 16 ? 16 : dlt)) + 16;
        s0[t] = (sa[t][j] + qrelS[qloc * 33 + idx]) * INV_SCALE;
      }
      float tm = fmaxf(fmaxf(s0[0], s0[1]), fmaxf(s0[2], s0[3]));
#pragma unroll
      for (int msk = 1; msk <= 8; msk <<= 1) tm = fmaxf(tm, __shfl_xor(tm, msk));
      float mnew = fmaxf(mreg[j], tm);
      float co = __expf(mreg[j] - mnew);
      float rs = 0.f, rl = 0.f;
#pragma unroll
      for (int t = 0; t < 4; ++t) {
        float pe = __expf(s0[t] - mnew);
        p[t][j] = pe;
        rs += pe;
        int kg = k64 + (t << 4) + c;
        if (kg - qg <= -16) rl += pe;
      }
#pragma unroll
      for (int msk = 1; msk <= 8; msk <<= 1) { rs += __shfl_xor(rs, msk); rl += __shfl_xor(rl, msk); }
      lreg[j] = lreg[j] * co + rs;
      lowreg[j] = lowreg[j] * co + rl;
      mreg[j] = mnew;
      corr[j] = co;
    }
#pragma unroll
    for (int dt = 0; dt < 4; ++dt)
#pragma unroll
      for (int j = 0; j < 4; ++j) acc[dt][j] *= corr[j];

    // P -> LDS (bf16, swizzled), then PV
#pragma unroll
    for (int t = 0; t < 4; ++t)
#pragma unroll
      for (int j = 0; j < 4; ++j) {
        int r16 = (g << 2) + j;
        int kl = (t << 4) + c;
        *(u16*)((char*)Ps + (wid << 11) + r16 * 128 + ((kl << 1) ^ ((r16 & 7) << 4))) = f2bf(p[t][j]);
      }
    bf16x8 ap[2];
#pragma unroll
    for (int kk = 0; kk < 2; ++kk)
      ap[kk] = *(const bf16x8*)((const char*)Ps + (wid << 11) + c * 128 +
                                ((((kk << 5) + (g << 3)) << 1) ^ ((c & 7) << 4)));
#pragma unroll
    for (int dt = 0; dt < 4; ++dt) {
      int row = (dt << 4) + c;
#pragma unroll
      for (int kk = 0; kk < 2; ++kk) {
        bf16x8 bv = *(const bf16x8*)((const char*)Vs + row * 128 +
                                     ((((kk << 5) + (g << 3)) << 1) ^ ((row & 7) << 4)));
        acc[dt] = MFMA16(ap[kk], bv, acc[dt]);
      }
    }
  }

  const int b = bh >> 3, h = bh & 7;
  float invl[4];
#pragma unroll
  for (int j = 0; j < 4; ++j) invl[j] = 1.f / lreg[j];
#pragma unroll
  for (int dt = 0; dt < 4; ++dt) {
    int d = (dt << 4) + c;
#pragma unroll
    for (int j = 0; j < 4; ++j) {
      int q = qbase + (wid << 4) + (g << 2) + j;
      float v = acc[dt][j] * invl[j];
      Xout[(((((size_t)b << 10) + q) << 9)) + (h << 6) + d] = f2bf(v);
    }
  }
  if (c == 0) {
#pragma unroll
    for (int j = 0; j < 4; ++j) {
      size_t rid = rowbase + qbase + (wid << 4) + (g << 2) + j;
      Mg[rid] = mreg[j]; Lg[rid] = lreg[j]; LOWg[rid] = lowreg[j];
    }
  }
}

// ---------------- band post-pass: add w2 (relative-V term) into Xout ----------------
__global__ void __launch_bounds__(256) post_rel(const u16* __restrict__ Qh, const u16* __restrict__ Kh,
                                                const float* __restrict__ qrel, const float* __restrict__ relv,
                                                const float* __restrict__ Mg, const float* __restrict__ Lg,
                                                const float* __restrict__ LOWg, u16* __restrict__ Xout) {
  __shared__ float rvS[33 * 64];
  const int tid = threadIdx.x, lane = tid & 63, wid = tid >> 6;
  for (int i = tid; i < 33 * 64; i += 256) rvS[i] = relv[i];
  __syncthreads();
  const size_t rid = (((size_t)blockIdx.x) << 2) + wid;
  const int bh = (int)(rid >> 10), q = (int)(rid & 1023);
  const int b = bh >> 3, h = bh & 7;
  const int d = lane;
  const float qd = bf2f(Qh[(rid << 6) + d]);
  const float m = Mg[rid];
  const float invl = 1.f / Lg[rid];
  const float lowp = LOWg[rid] * invl;
  float hp = 1.f - lowp;
  float w2 = lowp * rvS[d];
  const size_t bhbase = ((size_t)bh) << 10;
  for (int j = 1; j <= 31; ++j) {
    int kk = q - 16 + j;
    if ((unsigned)kk < 1024u) {
      float t = qd * bf2f(Kh[((bhbase + kk) << 6) + d]);
#pragma unroll
      for (int msk = 1; msk <= 32; msk <<= 1) t += __shfl_xor(t, msk);
      float pj = __expf((t + qrel[rid * 33 + j]) * INV_SCALE - m) * invl;
      hp -= pj;
      w2 += pj * rvS[(j << 6) + d];
    }
  }
  w2 += hp * rvS[(32 << 6) + d];
  size_t oi = (((((size_t)b << 10) + q) << 9)) + (h << 6) + d;
  Xout[oi] = f2bf(bf2f(Xout[oi]) + w2);
}

// ---------------- launch ----------------
extern "C" void kernel_launch(void* const* d_in, const int* in_sizes, int n_in,
                              void* d_out, int out_size, void* d_ws, size_t ws_size,
                              hipStream_t stream) {
  (void)in_sizes; (void)n_in; (void)out_size; (void)ws_size;
  const float* query = (const float*)d_in[0];
  const float* key   = (const float*)d_in[1];
  const float* value = (const float*)d_in[2];
  const float* Wq = (const float*)d_in[3];
  const float* bq = (const float*)d_in[4];
  const float* Wk = (const float*)d_in[5];
  const float* bk = (const float*)d_in[6];
  const float* Wv = (const float*)d_in[7];
  const float* bv = (const float*)d_in[8];
  const float* Wo = (const float*)d_in[9];
  const float* bo = (const float*)d_in[10];
  const float* relk = (const float*)d_in[11];
  const float* relv = (const float*)d_in[12];

  char* ws = (char*)d_ws;
  u16*   Xq    = (u16*)(ws + 0);
  u16*   Xk    = (u16*)(ws + 8388608);
  u16*   Xv    = (u16*)(ws + 16777216);
  u16*   Wqb   = (u16*)(ws + 25165824);
  u16*   Wkb   = (u16*)(ws + 25690112);
  u16*   Wvb   = (u16*)(ws + 26214400);
  u16*   Wob   = (u16*)(ws + 26738688);
  u16*   relkb = (u16*)(ws + 27262976);   // 33*64 bf16 (8 KB slot)
  u16*   Qh    = (u16*)(ws + 27271168);
  u16*   Kh    = (u16*)(ws + 35659776);
  u16*   Vh    = (u16*)(ws + 44048384);
  u16*   Vt    = (u16*)(ws + 52436992);
  float* qrelB = (float*)(ws + 60825600);
  float* Mg    = (float*)(ws + 69476352);
  float* Lg    = (float*)(ws + 69738496);
  float* LOWg  = (float*)(ws + 70000640);
  u16*   Xout  = (u16*)(ws + 70262784);

  conv3<<<12288, 256, 0, stream>>>(query, key, value, Xq, Xk, Xv);
  conv5<<<1027, 256, 0, stream>>>(Wq, Wk, Wv, Wo, relk, Wqb, Wkb, Wvb, Wob, relkb);
  gemm_bt<0><<<256, 256, 0, stream>>>(Xq, Wqb, bq, Qh);
  gemm_bt<0><<<256, 256, 0, stream>>>(Xk, Wkb, bk, Kh);
  gemm_bt<0><<<256, 256, 0, stream>>>(Xv, Wvb, bv, Vh);
  transpose_v<<<1024, 256, 0, stream>>>(Vh, Vt);
  qrel_gemm<<<1024, 256, 0, stream>>>(Qh, relkb, qrelB);
  flash_kernel<<<1024, 256, 0, stream>>>(Qh, Kh, Vt, qrelB, Xout, Mg, Lg, LOWg);
  post_rel<<<16384, 256, 0, stream>>>(Qh, Kh, qrelB, relv, Mg, Lg, LOWg, Xout);
  gemm_bt<1><<<256, 256, 0, stream>>>(Xout, Wob, bo, d_out);
}

// Round 2
// 197.365 us; speedup vs baseline: 1.7683x; 1.7683x over previous
//
#include <hip/hip_runtime.h>

typedef unsigned short u16;
typedef float f32x4 __attribute__((ext_vector_type(4)));
typedef __bf16 bf16x8 __attribute__((ext_vector_type(8)));

#define MFMA16(a, b, c) __builtin_amdgcn_mfma_f32_16x16x32_bf16((a), (b), (c), 0, 0, 0)

#define B_ 8
#define H_ 8
#define S_ 1024
static constexpr float INV_SCALE = 0.35355339059327373f; // 1/sqrt(B)

__device__ __forceinline__ u16 f2bf(float f) {
  unsigned u = __float_as_uint(f);
  return (u16)((u + 0x7fffu + ((u >> 16) & 1u)) >> 16);
}
__device__ __forceinline__ float bf2f(u16 h) {
  return __uint_as_float(((unsigned)h) << 16);
}
// async global->LDS, 16B per lane. LDS dest = wave-uniform base + lane*16.
__device__ __forceinline__ void gload16(const void* g, void* l) {
  __builtin_amdgcn_global_load_lds((__attribute__((address_space(1))) const void*)g,
                                   (__attribute__((address_space(3))) void*)l, 16, 0, 0);
}

// ---------------- converts ----------------
__global__ void __launch_bounds__(256) conv3(const float* __restrict__ q, const float* __restrict__ k,
                                             const float* __restrict__ v,
                                             u16* __restrict__ dq, u16* __restrict__ dk, u16* __restrict__ dv) {
  size_t i4 = (size_t)blockIdx.x * 256 + threadIdx.x;   // float4 index; 3*1048576 total
  int tsel = (int)(i4 >> 20);
  size_t off = (i4 & 1048575) << 2;
  const float* s = tsel == 0 ? q : (tsel == 1 ? k : v);
  u16* d = tsel == 0 ? dq : (tsel == 1 ? dk : dv);
  float4 f = *(const float4*)(s + off);
  uint2 o; u16* po = (u16*)&o;
  po[0] = f2bf(f.x); po[1] = f2bf(f.y); po[2] = f2bf(f.z); po[3] = f2bf(f.w);
  *(uint2*)(d + off) = o;
}

__global__ void __launch_bounds__(256) conv5(const float* __restrict__ s0, const float* __restrict__ s1,
                                             const float* __restrict__ s2, const float* __restrict__ s3,
                                             const float* __restrict__ s4,
                                             u16* __restrict__ d0, u16* __restrict__ d1, u16* __restrict__ d2,
                                             u16* __restrict__ d3, u16* __restrict__ d4) {
  size_t i = ((size_t)blockIdx.x * 256 + threadIdx.x) << 2;
  if (i >= 1050688) return; // 4*262144 + 33*64
  const float* s; u16* d; size_t off;
  if (i < 262144)       { s = s0; d = d0; off = i; }
  else if (i < 524288)  { s = s1; d = d1; off = i - 262144; }
  else if (i < 786432)  { s = s2; d = d2; off = i - 524288; }
  else if (i < 1048576) { s = s3; d = d3; off = i - 786432; }
  else                  { s = s4; d = d4; off = i - 1048576; }
  float4 f = *(const float4*)(s + off);
  uint2 o; u16* po = (u16*)&o;
  po[0] = f2bf(f.x); po[1] = f2bf(f.y); po[2] = f2bf(f.z); po[3] = f2bf(f.w);
  *(uint2*)(d + off) = o;
}

// ---------------- GEMM: C[M=8192][N=512] = A(bf16) @ W(bf16)^T + bias ----------------
// MODE 0: write bf16 head-split [B,H,S,64]; MODE 1: write fp32 row-major [M][512].
template <int MODE>
__global__ void __launch_bounds__(256) gemm_bt(const u16* __restrict__ A, const u16* __restrict__ W,
                                               const float* __restrict__ bias, void* __restrict__ out) {
  __shared__ u16 As[128 * 64];
  __shared__ u16 Bs[128 * 64];
  const int tid = threadIdx.x, lane = tid & 63, wid = tid >> 6;
  const int c = lane & 15, g = lane >> 4;
  const int bm = blockIdx.x >> 2, bn = blockIdx.x & 3;
  const int m0 = bm << 7, n0 = bn << 7;
  const int wrow = (wid >> 1) << 6, wcol = (wid & 1) << 6;

  const f32x4 ZF = {0.f, 0.f, 0.f, 0.f};
  f32x4 acc[4][4];
#pragma unroll
  for (int i = 0; i < 4; ++i)
#pragma unroll
    for (int j = 0; j < 4; ++j) acc[i][j] = ZF;

  for (int kt = 0; kt < 512; kt += 64) {
    __syncthreads();
#pragma unroll
    for (int i = 0; i < 4; ++i) {
      int Lb = ((wid << 2) | i) << 10;
      int L = Lb + lane * 16;
      int row = L >> 7;                                 // 0..127
      int off = (L & 127) ^ ((row & 7) << 4);           // pre-swizzled source
      gload16((const char*)A + ((((size_t)(m0 + row)) << 9) + kt) * 2 + off, (char*)As + Lb);
      gload16((const char*)W + ((((size_t)(n0 + row)) << 9) + kt) * 2 + off, (char*)Bs + Lb);
    }
    __syncthreads();
#pragma unroll
    for (int kk = 0; kk < 2; ++kk) {
      bf16x8 af[4], bfr[4];
#pragma unroll
      for (int rt = 0; rt < 4; ++rt) {
        int row = wrow + (rt << 4) + c;
        af[rt] = *(const bf16x8*)((const char*)As + row * 128 + (((kk << 6) | (g << 4)) ^ ((row & 7) << 4)));
      }
#pragma unroll
      for (int ct = 0; ct < 4; ++ct) {
        int row = wcol + (ct << 4) + c;
        bfr[ct] = *(const bf16x8*)((const char*)Bs + row * 128 + (((kk << 6) | (g << 4)) ^ ((row & 7) << 4)));
      }
#pragma unroll
      for (int rt = 0; rt < 4; ++rt)
#pragma unroll
        for (int ct = 0; ct < 4; ++ct) acc[rt][ct] = MFMA16(af[rt], bfr[ct], acc[rt][ct]);
    }
  }

#pragma unroll
  for (int rt = 0; rt < 4; ++rt)
#pragma unroll
    for (int ct = 0; ct < 4; ++ct) {
      int n = n0 + wcol + (ct << 4) + c;
      float bv = bias[n];
#pragma unroll
      for (int r = 0; r < 4; ++r) {
        int m = m0 + wrow + (rt << 4) + (g << 2) + r;
        float v = acc[rt][ct][r] + bv;
        if (MODE == 0) {
          int b = m >> 10, s = m & 1023, h = n >> 6, d = n & 63;
          ((u16*)out)[(((((size_t)(b * H_ + h)) << 10) + s) << 6) + d] = f2bf(v);
        } else {
          ((float*)out)[(((size_t)m) << 9) + n] = v;
        }
      }
    }
}

// ---------------- V transpose: [BH, S, 64] -> [BH, 64, S] ----------------
__global__ void __launch_bounds__(256) transpose_v(const u16* __restrict__ Vh, u16* __restrict__ Vt) {
  __shared__ u16 tile[64 * 68];
  const int t = threadIdx.x;
  const int bh = blockIdx.x >> 4, st = blockIdx.x & 15;
  {
    int sl = t >> 2, cc = t & 3;
    const u16* src = Vh + ((((size_t)bh << 10) + (st << 6) + sl) << 6) + (cc << 4);
    const uint2* s2 = (const uint2*)src;
    uint2* d2 = (uint2*)((char*)tile + sl * 136 + (cc << 5));
    d2[0] = s2[0]; d2[1] = s2[1]; d2[2] = s2[2]; d2[3] = s2[3];
  }
  __syncthreads();
  {
    int d = t >> 2, sc = t & 3;
    uint4 o0, o1; u16* p0 = (u16*)&o0; u16* p1 = (u16*)&o1;
#pragma unroll
    for (int i = 0; i < 8; ++i) {
      p0[i] = tile[(sc * 16 + i) * 68 + d];
      p1[i] = tile[(sc * 16 + 8 + i) * 68 + d];
    }
    u16* dst = Vt + ((((size_t)bh << 6) + d) << 10) + (st << 6) + (sc << 4);
    *(uint4*)dst = o0;
    *(uint4*)(dst + 8) = o1;
  }
}

// ---------------- qrel[row][r] = Q[row,:] . rel_k[r,:]  (rows=65536, r<33) ----------------
__global__ void __launch_bounds__(256) qrel_gemm(const u16* __restrict__ Qh, const u16* __restrict__ relkb,
                                                 float* __restrict__ qrelB) {
  const int lane = threadIdx.x & 63, wid = threadIdx.x >> 6;
  const int c = lane & 15, g = lane >> 4;
  const size_t rbase = (((size_t)blockIdx.x << 2) + wid) << 4;
  bf16x8 qa[2];
#pragma unroll
  for (int kk = 0; kk < 2; ++kk)
    qa[kk] = *(const bf16x8*)(Qh + ((rbase + c) << 6) + (kk << 5) + (g << 3));
  const f32x4 ZF = {0.f, 0.f, 0.f, 0.f};
  f32x4 acc[3] = {ZF, ZF, ZF};
#pragma unroll
  for (int ct = 0; ct < 3; ++ct) {
    int r = ct * 16 + c; if (r > 32) r = 32;  // clamp: cols>32 discarded
#pragma unroll
    for (int kk = 0; kk < 2; ++kk) {
      bf16x8 bfr = *(const bf16x8*)(relkb + (r << 6) + (kk << 5) + (g << 3));
      acc[ct] = MFMA16(qa[kk], bfr, acc[ct]);
    }
  }
#pragma unroll
  for (int ct = 0; ct < 3; ++ct)
#pragma unroll
    for (int r = 0; r < 4; ++r) {
      int col = ct * 16 + c;
      if (col < 33) qrelB[(rbase + (g << 2) + r) * 33 + col] = acc[ct][r];
    }
}

// ---------------- flash attention with relative-K bias + fused relative-V term ----------------
__global__ void __launch_bounds__(256) flash_kernel(const u16* __restrict__ Qh, const u16* __restrict__ Kh,
                                                    const u16* __restrict__ Vt, const float* __restrict__ qrel,
                                                    const float* __restrict__ relv, u16* __restrict__ Xout) {
  __shared__ u16 Ks[64 * 64];
  __shared__ u16 Vs[64 * 64];
  __shared__ u16 Ps[4 * 16 * 64];
  __shared__ float qrelS[64 * 33];
  __shared__ float bandS[64 * 33];   // [qloc][r]: pre-softmax band scores, r=1..31 used
  __shared__ float mS[64], invlS[64];

  const int tid = threadIdx.x, lane = tid & 63, wid = tid >> 6;
  const int c = lane & 15, g = lane >> 4;
  const int bh = blockIdx.x >> 4, qt = blockIdx.x & 15;
  const int qbase = qt << 6;
  const size_t rowbase = ((size_t)bh) << 10;

  for (int i = tid; i < 64 * 33; i += 256) {
    qrelS[i] = qrel[(rowbase + qbase) * 33 + i];
    bandS[i] = -1e30f;
  }

  const int qrow = qbase + (wid << 4) + c;
  bf16x8 qa[2];
#pragma unroll
  for (int kk = 0; kk < 2; ++kk)
    qa[kk] = *(const bf16x8*)(Qh + ((rowbase + qrow) << 6) + (kk << 5) + (g << 3));

  const f32x4 ZF = {0.f, 0.f, 0.f, 0.f};
  f32x4 acc[4] = {ZF, ZF, ZF, ZF};
  float mreg[4], lreg[4], lowreg[4];
#pragma unroll
  for (int j = 0; j < 4; ++j) { mreg[j] = -1e30f; lreg[j] = 0.f; lowreg[j] = 0.f; }

  for (int kt = 0; kt < 16; ++kt) {
    const int k64 = kt << 6;
    __syncthreads();
#pragma unroll
    for (int i = 0; i < 2; ++i) {
      int Lb2 = ((wid << 1) | i) << 10;
      int L = Lb2 + lane * 16;
      int row = L >> 7;                           // 0..63
      int off = (L & 127) ^ ((row & 7) << 4);
      gload16((const char*)Kh + ((rowbase + k64 + row) << 7) + off, (char*)Ks + Lb2);
      gload16((const char*)Vt + ((((size_t)bh << 6) + row) << 11) + (k64 << 1) + off, (char*)Vs + Lb2);
    }
    __syncthreads();

    // QK^T: 16 q-rows x 64 k-cols per wave
    f32x4 sa[4];
#pragma unroll
    for (int t = 0; t < 4; ++t) {
      sa[t] = ZF;
#pragma unroll
      for (int kk = 0; kk < 2; ++kk) {
        int row = (t << 4) + c;
        bf16x8 bk = *(const bf16x8*)((const char*)Ks + row * 128 + (((kk << 6) | (g << 4)) ^ ((row & 7) << 4)));
        sa[t] = MFMA16(qa[kk], bk, sa[t]);
      }
    }

    float p[4][4], corr[4];
#pragma unroll
    for (int j = 0; j < 4; ++j) {
      const int qloc = (wid << 4) + (g << 2) + j;
      const int qg = qbase + qloc;
      float s0[4];
#pragma unroll
      for (int t = 0; t < 4; ++t) {
        int kg = k64 + (t << 4) + c;
        int dlt = kg - qg;
        int idx = (dlt < -16 ? -16 : (dlt > 16 ? 16 : dlt)) + 16;
        s0[t] = (sa[t][j] + qrelS[qloc * 33 + idx]) * INV_SCALE;
        // record banded scores (single-k relative buckets r=1..31)
        if (dlt > -16 && dlt < 16) bandS[qloc * 33 + dlt + 16] = s0[t];
      }
      float tm = fmaxf(fmaxf(s0[0], s0[1]), fmaxf(s0[2], s0[3]));
#pragma unroll
      for (int msk = 1; msk <= 8; msk <<= 1) tm = fmaxf(tm, __shfl_xor(tm, msk));
      float mnew = fmaxf(mreg[j], tm);
      float co = __expf(mreg[j] - mnew);
      float rs = 0.f, rl = 0.f;
#pragma unroll
      for (int t = 0; t < 4; ++t) {
        float pe = __expf(s0[t] - mnew);
        p[t][j] = pe;
        rs += pe;
        int kg = k64 + (t << 4) + c;
        if (kg - qg <= -16) rl += pe;
      }
#pragma unroll
      for (int msk = 1; msk <= 8; msk <<= 1) { rs += __shfl_xor(rs, msk); rl += __shfl_xor(rl, msk); }
      lreg[j] = lreg[j] * co + rs;
      lowreg[j] = lowreg[j] * co + rl;
      mreg[j] = mnew;
      corr[j] = co;
    }
#pragma unroll
    for (int dt = 0; dt < 4; ++dt)
#pragma unroll
      for (int j = 0; j < 4; ++j) acc[dt][j] *= corr[j];

    // P -> LDS (bf16, swizzled), then PV
#pragma unroll
    for (int t = 0; t < 4; ++t)
#pragma unroll
      for (int j = 0; j < 4; ++j) {
        int r16 = (g << 2) + j;
        int kl = (t << 4) + c;
        *(u16*)((char*)Ps + (wid << 11) + r16 * 128 + ((kl << 1) ^ ((r16 & 7) << 4))) = f2bf(p[t][j]);
      }
    bf16x8 ap[2];
#pragma unroll
    for (int kk = 0; kk < 2; ++kk)
      ap[kk] = *(const bf16x8*)((const char*)Ps + (wid << 11) + c * 128 +
                                ((((kk << 5) + (g << 3)) << 1) ^ ((c & 7) << 4)));
#pragma unroll
    for (int dt = 0; dt < 4; ++dt) {
      int row = (dt << 4) + c;
#pragma unroll
      for (int kk = 0; kk < 2; ++kk) {
        bf16x8 bv = *(const bf16x8*)((const char*)Vs + row * 128 +
                                     ((((kk << 5) + (g << 3)) << 1) ^ ((row & 7) << 4)));
        acc[dt] = MFMA16(ap[kk], bv, acc[dt]);
      }
    }
  }

  // ---- epilogue: fused relative-V (w2) term ----
  if (c == 0) {
#pragma unroll
    for (int j = 0; j < 4; ++j) {
      int qloc = (wid << 4) + (g << 2) + j;
      mS[qloc] = mreg[j];
      invlS[qloc] = 1.f / lreg[j];
    }
  }
  __syncthreads();
  // convert band scores -> final probabilities (in place)
  for (int i = tid; i < 64 * 31; i += 256) {
    int q = i / 31, rr = i - q * 31 + 1;
    float s = bandS[q * 33 + rr];
    bandS[q * 33 + rr] = __expf(s - mS[q]) * invlS[q];
  }
  __syncthreads();

  const int b = bh >> 3, h = bh & 7;
  float w2[4][4];   // [dt][j]
  float psum[4];
#pragma unroll
  for (int j = 0; j < 4; ++j) {
    psum[j] = 0.f;
#pragma unroll
    for (int dt = 0; dt < 4; ++dt) w2[dt][j] = 0.f;
  }
  const int qlocb = (wid << 4) + (g << 2);
  for (int r = 1; r <= 31; ++r) {
    float rvv[4];
#pragma unroll
    for (int dt = 0; dt < 4; ++dt) rvv[dt] = relv[(r << 6) + (dt << 4) + c];
#pragma unroll
    for (int j = 0; j < 4; ++j) {
      float pr = bandS[(qlocb + j) * 33 + r];
      psum[j] += pr;
#pragma unroll
      for (int dt = 0; dt < 4; ++dt) w2[dt][j] += pr * rvv[dt];
    }
  }
#pragma unroll
  for (int j = 0; j < 4; ++j) {
    float il = 1.f / lreg[j];
    float lowp = lowreg[j] * il;
    float hp = 1.f - lowp - psum[j];
    int q = qbase + qlocb + j;
#pragma unroll
    for (int dt = 0; dt < 4; ++dt) {
      int d = (dt << 4) + c;
      float v = acc[dt][j] * il + w2[dt][j] + lowp * relv[d] + hp * relv[(32 << 6) + d];
      Xout[(((((size_t)b << 10) + q) << 9)) + (h << 6) + d] = f2bf(v);
    }
  }
}

// ---------------- launch ----------------
extern "C" void kernel_launch(void* const* d_in, const int* in_sizes, int n_in,
                              void* d_out, int out_size, void* d_ws, size_t ws_size,
                              hipStream_t stream) {
  (void)in_sizes; (void)n_in; (void)out_size; (void)ws_size;
  const float* query = (const float*)d_in[0];
  const float* key   = (const float*)d_in[1];
  const float* value = (const float*)d_in[2];
  const float* Wq = (const float*)d_in[3];
  const float* bq = (const float*)d_in[4];
  const float* Wk = (const float*)d_in[5];
  const float* bk = (const float*)d_in[6];
  const float* Wv = (const float*)d_in[7];
  const float* bv = (const float*)d_in[8];
  const float* Wo = (const float*)d_in[9];
  const float* bo = (const float*)d_in[10];
  const float* relk = (const float*)d_in[11];
  const float* relv = (const float*)d_in[12];

  char* ws = (char*)d_ws;
  u16*   Xq    = (u16*)(ws + 0);
  u16*   Xk    = (u16*)(ws + 8388608);
  u16*   Xv    = (u16*)(ws + 16777216);
  u16*   Wqb   = (u16*)(ws + 25165824);
  u16*   Wkb   = (u16*)(ws + 25690112);
  u16*   Wvb   = (u16*)(ws + 26214400);
  u16*   Wob   = (u16*)(ws + 26738688);
  u16*   relkb = (u16*)(ws + 27262976);   // 33*64 bf16 (8 KB slot)
  u16*   Qh    = (u16*)(ws + 27271168);
  u16*   Kh    = (u16*)(ws + 35659776);
  u16*   Vh    = (u16*)(ws + 44048384);
  u16*   Vt    = (u16*)(ws + 52436992);
  float* qrelB = (float*)(ws + 60825600);
  u16*   Xout  = (u16*)(ws + 70262784);

  conv3<<<12288, 256, 0, stream>>>(query, key, value, Xq, Xk, Xv);
  conv5<<<1027, 256, 0, stream>>>(Wq, Wk, Wv, Wo, relk, Wqb, Wkb, Wvb, Wob, relkb);
  gemm_bt<0><<<256, 256, 0, stream>>>(Xq, Wqb, bq, Qh);
  gemm_bt<0><<<256, 256, 0, stream>>>(Xk, Wkb, bk, Kh);
  gemm_bt<0><<<256, 256, 0, stream>>>(Xv, Wvb, bv, Vh);
  transpose_v<<<1024, 256, 0, stream>>>(Vh, Vt);
  qrel_gemm<<<1024, 256, 0, stream>>>(Qh, relkb, qrelB);
  flash_kernel<<<1024, 256, 0, stream>>>(Qh, Kh, Vt, qrelB, relv, Xout);
  gemm_bt<1><<<256, 256, 0, stream>>>(Xout, Wob, bo, d_out);
}

// Round 3
// 135.125 us; speedup vs baseline: 2.5827x; 1.4606x over previous
//
#include <hip/hip_runtime.h>

typedef unsigned short u16;
typedef float f32x4 __attribute__((ext_vector_type(4)));
typedef __bf16 bf16x8 __attribute__((ext_vector_type(8)));

#define MFMA16(a, b, c) __builtin_amdgcn_mfma_f32_16x16x32_bf16((a), (b), (c), 0, 0, 0)

#define B_ 8
#define H_ 8
#define S_ 1024

__device__ __forceinline__ u16 f2bf(float f) {
  unsigned u = __float_as_uint(f);
  return (u16)((u + 0x7fffu + ((u >> 16) & 1u)) >> 16);
}
__device__ __forceinline__ float bf2f(u16 h) {
  return __uint_as_float(((unsigned)h) << 16);
}
// async global->LDS, 16B per lane. LDS dest = wave-uniform base + lane*16.
__device__ __forceinline__ void gload16(const void* g, void* l) {
  __builtin_amdgcn_global_load_lds((__attribute__((address_space(1))) const void*)g,
                                   (__attribute__((address_space(3))) void*)l, 16, 0, 0);
}

// ---------------- converts ----------------
__global__ void __launch_bounds__(256) conv3(const float* __restrict__ q, const float* __restrict__ k,
                                             const float* __restrict__ v,
                                             u16* __restrict__ dq, u16* __restrict__ dk, u16* __restrict__ dv) {
  size_t i4 = (size_t)blockIdx.x * 256 + threadIdx.x;   // float4 index; 3*1048576 total
  int tsel = (int)(i4 >> 20);
  size_t off = (i4 & 1048575) << 2;
  const float* s = tsel == 0 ? q : (tsel == 1 ? k : v);
  u16* d = tsel == 0 ? dq : (tsel == 1 ? dk : dv);
  float4 f = *(const float4*)(s + off);
  uint2 o; u16* po = (u16*)&o;
  po[0] = f2bf(f.x); po[1] = f2bf(f.y); po[2] = f2bf(f.z); po[3] = f2bf(f.w);
  *(uint2*)(d + off) = o;
}

__global__ void __launch_bounds__(256) conv5(const float* __restrict__ s0, const float* __restrict__ s1,
                                             const float* __restrict__ s2, const float* __restrict__ s3,
                                             const float* __restrict__ s4,
                                             u16* __restrict__ d0, u16* __restrict__ d1, u16* __restrict__ d2,
                                             u16* __restrict__ d3, u16* __restrict__ d4) {
  size_t i = ((size_t)blockIdx.x * 256 + threadIdx.x) << 2;
  if (i >= 1050688) return; // 4*262144 + 33*64
  const float* s; u16* d; size_t off;
  if (i < 262144)       { s = s0; d = d0; off = i; }
  else if (i < 524288)  { s = s1; d = d1; off = i - 262144; }
  else if (i < 786432)  { s = s2; d = d2; off = i - 524288; }
  else if (i < 1048576) { s = s3; d = d3; off = i - 786432; }
  else                  { s = s4; d = d4; off = i - 1048576; }
  float4 f = *(const float4*)(s + off);
  uint2 o; u16* po = (u16*)&o;
  po[0] = f2bf(f.x); po[1] = f2bf(f.y); po[2] = f2bf(f.z); po[3] = f2bf(f.w);
  *(uint2*)(d + off) = o;
}

// ---------------- GEMM: C[M=8192][N=512] = A(bf16) @ W(bf16)^T + bias ----------------
// MODE 0: bf16 head-split [B,H,S,64]; MODE 1: fp32 row-major [M][512];
// MODE 2: bf16 transposed head-split [B*H, 64, S]  (for V).
template <int MODE>
__global__ void __launch_bounds__(256) gemm_bt(const u16* __restrict__ A, const u16* __restrict__ W,
                                               const float* __restrict__ bias, void* __restrict__ out) {
  __shared__ u16 As[128 * 64];
  __shared__ u16 Bs[128 * 64];
  const int tid = threadIdx.x, lane = tid & 63, wid = tid >> 6;
  const int c = lane & 15, g = lane >> 4;
  const int bm = blockIdx.x >> 2, bn = blockIdx.x & 3;
  const int m0 = bm << 7, n0 = bn << 7;
  const int wrow = (wid >> 1) << 6, wcol = (wid & 1) << 6;

  const f32x4 ZF = {0.f, 0.f, 0.f, 0.f};
  f32x4 acc[4][4];
#pragma unroll
  for (int i = 0; i < 4; ++i)
#pragma unroll
    for (int j = 0; j < 4; ++j) acc[i][j] = ZF;

  for (int kt = 0; kt < 512; kt += 64) {
    __syncthreads();
#pragma unroll
    for (int i = 0; i < 4; ++i) {
      int Lb = ((wid << 2) | i) << 10;
      int L = Lb + lane * 16;
      int row = L >> 7;                                 // 0..127
      int off = (L & 127) ^ ((row & 7) << 4);           // pre-swizzled source
      gload16((const char*)A + ((((size_t)(m0 + row)) << 9) + kt) * 2 + off, (char*)As + Lb);
      gload16((const char*)W + ((((size_t)(n0 + row)) << 9) + kt) * 2 + off, (char*)Bs + Lb);
    }
    __syncthreads();
#pragma unroll
    for (int kk = 0; kk < 2; ++kk) {
      bf16x8 af[4], bfr[4];
#pragma unroll
      for (int rt = 0; rt < 4; ++rt) {
        int row = wrow + (rt << 4) + c;
        af[rt] = *(const bf16x8*)((const char*)As + row * 128 + (((kk << 6) | (g << 4)) ^ ((row & 7) << 4)));
      }
#pragma unroll
      for (int ct = 0; ct < 4; ++ct) {
        int row = wcol + (ct << 4) + c;
        bfr[ct] = *(const bf16x8*)((const char*)Bs + row * 128 + (((kk << 6) | (g << 4)) ^ ((row & 7) << 4)));
      }
#pragma unroll
      for (int rt = 0; rt < 4; ++rt)
#pragma unroll
        for (int ct = 0; ct < 4; ++ct) acc[rt][ct] = MFMA16(af[rt], bfr[ct], acc[rt][ct]);
    }
  }

#pragma unroll
  for (int rt = 0; rt < 4; ++rt)
#pragma unroll
    for (int ct = 0; ct < 4; ++ct) {
      int n = n0 + wcol + (ct << 4) + c;
      float bv = bias[n];
      if (MODE == 2) {
        int b2 = m0 >> 10;
        int sbase = (m0 & 1023) + wrow + (rt << 4) + (g << 2);
        int h2 = n >> 6, d2 = n & 63;
        uint2 o; u16* po = (u16*)&o;
#pragma unroll
        for (int r = 0; r < 4; ++r) po[r] = f2bf(acc[rt][ct][r] + bv);
        *(uint2*)((u16*)out + ((((size_t)((b2 << 3) + h2) << 6) + d2) << 10) + sbase) = o;
      } else {
#pragma unroll
        for (int r = 0; r < 4; ++r) {
          int m = m0 + wrow + (rt << 4) + (g << 2) + r;
          float v = acc[rt][ct][r] + bv;
          if (MODE == 0) {
            int b = m >> 10, s = m & 1023, h = n >> 6, d = n & 63;
            ((u16*)out)[(((((size_t)(b * H_ + h)) << 10) + s) << 6) + d] = f2bf(v);
          } else {
            ((float*)out)[(((size_t)m) << 9) + n] = v;
          }
        }
      }
    }
}

// ---------------- qrel[row][r] = Q[row,:] . rel_k[r,:]  (rows=65536, r<33) ----------------
__global__ void __launch_bounds__(256) qrel_gemm(const u16* __restrict__ Qh, const u16* __restrict__ relkb,
                                                 float* __restrict__ qrelB) {
  const int lane = threadIdx.x & 63, wid = threadIdx.x >> 6;
  const int c = lane & 15, g = lane >> 4;
  const size_t rbase = (((size_t)blockIdx.x << 2) + wid) << 4;
  bf16x8 qa[2];
#pragma unroll
  for (int kk = 0; kk < 2; ++kk)
    qa[kk] = *(const bf16x8*)(Qh + ((rbase + c) << 6) + (kk << 5) + (g << 3));
  const f32x4 ZF = {0.f, 0.f, 0.f, 0.f};
  f32x4 acc[3] = {ZF, ZF, ZF};
#pragma unroll
  for (int ct = 0; ct < 3; ++ct) {
    int r = ct * 16 + c; if (r > 32) r = 32;  // clamp: cols>32 discarded
#pragma unroll
    for (int kk = 0; kk < 2; ++kk) {
      bf16x8 bfr = *(const bf16x8*)(relkb + (r << 6) + (kk << 5) + (g << 3));
      acc[ct] = MFMA16(qa[kk], bfr, acc[ct]);
    }
  }
#pragma unroll
  for (int ct = 0; ct < 3; ++ct)
#pragma unroll
    for (int r = 0; r < 4; ++r) {
      int col = ct * 16 + c;
      if (col < 33) qrelB[(rbase + (g << 2) + r) * 33 + col] = acc[ct][r];
    }
}

// ---------------- flash attention, swapped-MFMA, fixed-max exp2 softmax ----------------
// lane (c,g) owns q = qbase + wid*16 + c for scores, sums, and output.
__global__ void __launch_bounds__(256) flash_kernel(const u16* __restrict__ Qh, const u16* __restrict__ Kh,
                                                    const u16* __restrict__ Vt, const float* __restrict__ qrel,
                                                    const float* __restrict__ relv, u16* __restrict__ Xout) {
  __shared__ u16 Ks[2][64 * 64];
  __shared__ u16 Vs[2][64 * 64];
  __shared__ u16 Ps[64 * 64];
  __shared__ float qrelS[64 * 34];   // qrel * K1 - C, stride 34
  __shared__ float bandS[64 * 34];   // band scores s' (exp2-domain, incl -C), stride 34
  __shared__ u16 rvTS[64 * 32];      // rv^T [d][r], bf16
  __shared__ float rv32S[64];

  const int tid = threadIdx.x, lane = tid & 63, wid = tid >> 6;
  const int c = lane & 15, g = lane >> 4;
  // XCD swizzle: contiguous work chunks per XCD -> same-bh blocks share an L2
  const int swz = ((blockIdx.x & 7) << 7) | (blockIdx.x >> 3);
  const int bh = swz >> 4, qt = swz & 15;
  const int qbase = qt << 6;
  const size_t rowbase = ((size_t)bh) << 10;
  const int qloc = (wid << 4) + c;

  const float K1 = 0.51013619f;   // (1/sqrt(8)) * log2(e)
  const float C0 = 24.0f;

  for (int i = tid; i < 64 * 33; i += 256) {
    int qq = i / 33, rr = i - qq * 33;
    qrelS[qq * 34 + rr] = qrel[(rowbase + qbase) * 33 + i] * K1 - C0;
  }
  for (int i = tid; i < 64 * 34; i += 256) bandS[i] = -1e30f;
  for (int i = tid; i < 64 * 32; i += 256) {
    int dd = i >> 5, rr = i & 31;
    rvTS[i] = f2bf(relv[(rr << 6) + dd]);
  }
  if (tid < 64) rv32S[tid] = relv[(32 << 6) + tid];

  bf16x8 qa[2];
  {
    const u16* qptr = Qh + ((rowbase + qbase + qloc) << 6);
    qa[0] = *(const bf16x8*)(qptr + (g << 3));
    qa[1] = *(const bf16x8*)(qptr + 32 + (g << 3));
  }

#define STAGE(buf, kt_) do { \
    const int k64_ = (kt_) << 6; \
    _Pragma("unroll") \
    for (int i_ = 0; i_ < 2; ++i_) { \
      int Lb_ = ((wid << 1) | i_) << 10; \
      int L_ = Lb_ + lane * 16; \
      int row_ = L_ >> 7; \
      int off_ = (L_ & 127) ^ ((row_ & 7) << 4); \
      gload16((const char*)Kh + ((rowbase + k64_ + row_) << 7) + off_, (char*)Ks[buf] + Lb_); \
      gload16((const char*)Vt + ((((size_t)bh << 6) + row_) << 11) + (k64_ << 1) + off_, (char*)Vs[buf] + Lb_); \
    } \
  } while (0)

  STAGE(0, 0);
  __syncthreads();   // covers prologue LDS fills + first stage

  const float bias_lo = qrelS[qloc * 34 + 0];
  const float bias_hi = qrelS[qloc * 34 + 32];
  const f32x4 ZF = {0.f, 0.f, 0.f, 0.f};
  f32x4 acc[4] = {ZF, ZF, ZF, ZF};
  float lsum = 0.f, lowsum = 0.f;

  for (int kt = 0; kt < 16; ++kt) {
    const int cur = kt & 1;
    if (kt < 15) STAGE(cur ^ 1, kt + 1);   // prefetch hides under compute

    // QK^T swapped: sa[t] holds S[k-row = t*16+g*4+j][q = c]
    f32x4 sa[4];
#pragma unroll
    for (int t = 0; t < 4; ++t) {
      sa[t] = ZF;
#pragma unroll
      for (int kk = 0; kk < 2; ++kk) {
        int row = (t << 4) + c;
        bf16x8 bk = *(const bf16x8*)((const char*)Ks[cur] + row * 128 + (((kk << 6) | (g << 4)) ^ ((row & 7) << 4)));
        sa[t] = MFMA16(bk, qa[kk], sa[t]);
      }
    }

    const int D0 = (kt << 6) - qbase;
    float p[4][4];
    if (D0 >= 128) {            // all dlt >= 17: high bucket, uniform bias
      float s = 0.f;
#pragma unroll
      for (int t = 0; t < 4; ++t)
#pragma unroll
        for (int j = 0; j < 4; ++j) {
          float pe = __builtin_amdgcn_exp2f(fmaf(sa[t][j], K1, bias_hi));
          p[t][j] = pe; s += pe;
        }
      lsum += s;
    } else if (D0 <= -128) {    // all dlt <= -17: low bucket
      float s = 0.f;
#pragma unroll
      for (int t = 0; t < 4; ++t)
#pragma unroll
        for (int j = 0; j < 4; ++j) {
          float pe = __builtin_amdgcn_exp2f(fmaf(sa[t][j], K1, bias_lo));
          p[t][j] = pe; s += pe;
        }
      lsum += s; lowsum += s;
    } else {                    // boundary tiles (3 of 16)
#pragma unroll
      for (int t = 0; t < 4; ++t)
#pragma unroll
        for (int j = 0; j < 4; ++j) {
          int dlt = D0 + (t << 4) + (g << 2) + j - qloc;
          int idx = dlt < -16 ? 0 : (dlt > 16 ? 32 : dlt + 16);
          float sp = fmaf(sa[t][j], K1, qrelS[qloc * 34 + idx]);
          float pe = __builtin_amdgcn_exp2f(sp);
          p[t][j] = pe;
          lsum += pe;
          if (dlt <= -16) lowsum += pe;
          if (dlt > -16 && dlt < 16) bandS[qloc * 34 + dlt + 16] = sp;
        }
    }

    // P -> LDS: 4x ds_write_b64, row = own q, swizzled on row&7
#pragma unroll
    for (int t = 0; t < 4; ++t) {
      uint2 pk; u16* pp = (u16*)&pk;
      pp[0] = f2bf(p[t][0]); pp[1] = f2bf(p[t][1]); pp[2] = f2bf(p[t][2]); pp[3] = f2bf(p[t][3]);
      *(uint2*)((char*)Ps + qloc * 128 + (((t << 5) | (g << 3)) ^ ((c & 7) << 4))) = pk;
    }
    // PV swapped: acc[dt] holds O[d = dt*16+g*4+j][q = c]
    bf16x8 pb0 = *(const bf16x8*)((const char*)Ps + qloc * 128 + ((g << 4) ^ ((c & 7) << 4)));
    bf16x8 pb1 = *(const bf16x8*)((const char*)Ps + qloc * 128 + ((64 | (g << 4)) ^ ((c & 7) << 4)));
#pragma unroll
    for (int dt = 0; dt < 4; ++dt) {
      int row = (dt << 4) + c;
      bf16x8 av0 = *(const bf16x8*)((const char*)Vs[cur] + row * 128 + ((g << 4) ^ ((row & 7) << 4)));
      bf16x8 av1 = *(const bf16x8*)((const char*)Vs[cur] + row * 128 + ((64 | (g << 4)) ^ ((row & 7) << 4)));
      acc[dt] = MFMA16(av0, pb0, acc[dt]);
      acc[dt] = MFMA16(av1, pb1, acc[dt]);
    }
    __syncthreads();   // drains prefetch vmcnt + protects dbuf swap
  }

  // ---- epilogue (all wave-local per q) ----
  lsum += __shfl_xor(lsum, 16);  lsum += __shfl_xor(lsum, 32);
  lowsum += __shfl_xor(lowsum, 16); lowsum += __shfl_xor(lowsum, 32);
  const float inv = 1.f / lsum;
  const float lowp = lowsum * inv;

  float psum = 0.f;
#pragma unroll
  for (int i = 0; i < 8; ++i) {
    int r = (g << 3) + i;
    float pv;
    if (i == 0 && g == 0) pv = lowp;
    else if (i == 0) { pv = __builtin_amdgcn_exp2f(bandS[qloc * 34 + r]) * inv; psum += pv; }
    else { pv = __builtin_amdgcn_exp2f(bandS[qloc * 34 + r]) * inv; psum += pv; }
    Ps[qloc * 64 + r] = f2bf(pv);
  }
  psum += __shfl_xor(psum, 16); psum += __shfl_xor(psum, 32);
  const float hp = 1.f - lowp - psum;

#pragma unroll
  for (int dt = 0; dt < 4; ++dt)
#pragma unroll
    for (int j = 0; j < 4; ++j) acc[dt][j] *= inv;

  // w2 band+low via MFMA: acc += rv^T[d][r] * Pband[r][q]
  bf16x8 pb2 = *(const bf16x8*)(Ps + qloc * 64 + (g << 3));
#pragma unroll
  for (int dt = 0; dt < 4; ++dt) {
    bf16x8 av = *(const bf16x8*)(rvTS + (((dt << 4) + c) << 5) + (g << 3));
    acc[dt] = MFMA16(av, pb2, acc[dt]);
  }

  const int b = bh >> 3, h = bh & 7;
  const int q = qbase + qloc;
  u16* xb = Xout + ((((size_t)b << 10) + q) << 9) + (h << 6);
#pragma unroll
  for (int dt = 0; dt < 4; ++dt) {
    int d0 = (dt << 4) + (g << 2);
    uint2 o; u16* po = (u16*)&o;
#pragma unroll
    for (int j = 0; j < 4; ++j) po[j] = f2bf(acc[dt][j] + hp * rv32S[d0 + j]);
    *(uint2*)(xb + d0) = o;
  }
#undef STAGE
}

// ---------------- launch ----------------
extern "C" void kernel_launch(void* const* d_in, const int* in_sizes, int n_in,
                              void* d_out, int out_size, void* d_ws, size_t ws_size,
                              hipStream_t stream) {
  (void)in_sizes; (void)n_in; (void)out_size; (void)ws_size;
  const float* query = (const float*)d_in[0];
  const float* key   = (const float*)d_in[1];
  const float* value = (const float*)d_in[2];
  const float* Wq = (const float*)d_in[3];
  const float* bq = (const float*)d_in[4];
  const float* Wk = (const float*)d_in[5];
  const float* bk = (const float*)d_in[6];
  const float* Wv = (const float*)d_in[7];
  const float* bv = (const float*)d_in[8];
  const float* Wo = (const float*)d_in[9];
  const float* bo = (const float*)d_in[10];
  const float* relk = (const float*)d_in[11];
  const float* relv = (const float*)d_in[12];

  char* ws = (char*)d_ws;
  u16*   Xq    = (u16*)(ws + 0);
  u16*   Xk    = (u16*)(ws + 8388608);
  u16*   Xv    = (u16*)(ws + 16777216);
  u16*   Wqb   = (u16*)(ws + 25165824);
  u16*   Wkb   = (u16*)(ws + 25690112);
  u16*   Wvb   = (u16*)(ws + 26214400);
  u16*   Wob   = (u16*)(ws + 26738688);
  u16*   relkb = (u16*)(ws + 27262976);   // 33*64 bf16 (8 KB slot)
  u16*   Qh    = (u16*)(ws + 27271168);
  u16*   Kh    = (u16*)(ws + 35659776);
  u16*   Vt    = (u16*)(ws + 52436992);
  float* qrelB = (float*)(ws + 60825600);
  u16*   Xout  = (u16*)(ws + 70262784);

  conv3<<<12288, 256, 0, stream>>>(query, key, value, Xq, Xk, Xv);
  conv5<<<1027, 256, 0, stream>>>(Wq, Wk, Wv, Wo, relk, Wqb, Wkb, Wvb, Wob, relkb);
  gemm_bt<0><<<256, 256, 0, stream>>>(Xq, Wqb, bq, Qh);
  gemm_bt<0><<<256, 256, 0, stream>>>(Xk, Wkb, bk, Kh);
  gemm_bt<2><<<256, 256, 0, stream>>>(Xv, Wvb, bv, Vt);
  qrel_gemm<<<1024, 256, 0, stream>>>(Qh, relkb, qrelB);
  flash_kernel<<<1024, 256, 0, stream>>>(Qh, Kh, Vt, qrelB, relv, Xout);
  gemm_bt<1><<<256, 256, 0, stream>>>(Xout, Wob, bo, d_out);
}

// Round 4
// 97.121 us; speedup vs baseline: 3.5934x; 1.3913x over previous
//
#include <hip/hip_runtime.h>

typedef unsigned short u16;
typedef float f32x4 __attribute__((ext_vector_type(4)));
typedef __bf16 bf16x8 __attribute__((ext_vector_type(8)));

#define MFMA16(a, b, c) __builtin_amdgcn_mfma_f32_16x16x32_bf16((a), (b), (c), 0, 0, 0)

#define B_ 8
#define H_ 8
#define S_ 1024

__device__ __forceinline__ u16 f2bf(float f) {
  unsigned u = __float_as_uint(f);
  return (u16)((u + 0x7fffu + ((u >> 16) & 1u)) >> 16);
}
// pack 2 f32 -> 2 bf16 in one instr (dst.lo = a, dst.hi = b)
__device__ __forceinline__ unsigned cvtpk(float a, float b) {
  unsigned r;
  asm("v_cvt_pk_bf16_f32 %0, %1, %2" : "=v"(r) : "v"(a), "v"(b));
  return r;
}
// async global->LDS, 16B per lane. LDS dest = wave-uniform base + lane*16.
__device__ __forceinline__ void gload16(const void* g, void* l) {
  __builtin_amdgcn_global_load_lds((__attribute__((address_space(1))) const void*)g,
                                   (__attribute__((address_space(3))) void*)l, 16, 0, 0);
}

// ---------------- all fp32->bf16 converts in one dispatch ----------------
__global__ void __launch_bounds__(256) convAll(const float* __restrict__ q, const float* __restrict__ k,
                                               const float* __restrict__ v, const float* __restrict__ Wq,
                                               const float* __restrict__ Wk, const float* __restrict__ Wv,
                                               const float* __restrict__ Wo, const float* __restrict__ relk,
                                               u16* __restrict__ dq, u16* __restrict__ dk, u16* __restrict__ dv,
                                               u16* __restrict__ dWq, u16* __restrict__ dWk, u16* __restrict__ dWv,
                                               u16* __restrict__ dWo, u16* __restrict__ drelk) {
  const int bid = blockIdx.x;
  const float* s; u16* d; size_t off;
  if (bid < 12288) {
    size_t i4 = (size_t)bid * 256 + threadIdx.x;   // 3*1048576 float4s
    int tsel = (int)(i4 >> 20);
    off = (i4 & 1048575) << 2;
    s = tsel == 0 ? q : (tsel == 1 ? k : v);
    d = tsel == 0 ? dq : (tsel == 1 ? dk : dv);
  } else {
    size_t i = ((size_t)(bid - 12288) * 256 + threadIdx.x) << 2;
    if (i >= 1050688) return; // 4*262144 + 33*64
    if (i < 262144)       { s = Wq; d = dWq; off = i; }
    else if (i < 524288)  { s = Wk; d = dWk; off = i - 262144; }
    else if (i < 786432)  { s = Wv; d = dWv; off = i - 524288; }
    else if (i < 1048576) { s = Wo; d = dWo; off = i - 786432; }
    else                  { s = relk; d = drelk; off = i - 1048576; }
  }
  float4 f = *(const float4*)(s + off);
  uint2 o;
  o.x = cvtpk(f.x, f.y);
  o.y = cvtpk(f.z, f.w);
  *(uint2*)(d + off) = o;
}

// ---------------- fused Q/K/V projection GEMM (768 blocks) ----------------
// seg 0: Q -> bf16 head-split [B,H,S,64]; seg 1: K same; seg 2: V -> transposed [B*H,64,S].
__global__ void __launch_bounds__(256) qkv_gemm(const u16* __restrict__ Xq, const u16* __restrict__ Xk,
                                                const u16* __restrict__ Xv, const u16* __restrict__ Wqb,
                                                const u16* __restrict__ Wkb, const u16* __restrict__ Wvb,
                                                const float* __restrict__ bq, const float* __restrict__ bk,
                                                const float* __restrict__ bv, u16* __restrict__ Qh,
                                                u16* __restrict__ Kh, u16* __restrict__ Vt) {
  __shared__ u16 As[128 * 64];
  __shared__ u16 Bs[128 * 64];
  const int seg = blockIdx.x >> 8, bid = blockIdx.x & 255;
  const u16* A = seg == 0 ? Xq : (seg == 1 ? Xk : Xv);
  const u16* W = seg == 0 ? Wqb : (seg == 1 ? Wkb : Wvb);
  const float* bias = seg == 0 ? bq : (seg == 1 ? bk : bv);
  const int tid = threadIdx.x, lane = tid & 63, wid = tid >> 6;
  const int c = lane & 15, g = lane >> 4;
  const int bm = bid >> 2, bn = bid & 3;
  const int m0 = bm << 7, n0 = bn << 7;
  const int wrow = (wid >> 1) << 6, wcol = (wid & 1) << 6;

  const f32x4 ZF = {0.f, 0.f, 0.f, 0.f};
  f32x4 acc[4][4];
#pragma unroll
  for (int i = 0; i < 4; ++i)
#pragma unroll
    for (int j = 0; j < 4; ++j) acc[i][j] = ZF;

  for (int kt = 0; kt < 512; kt += 64) {
    __syncthreads();
#pragma unroll
    for (int i = 0; i < 4; ++i) {
      int Lb = ((wid << 2) | i) << 10;
      int L = Lb + lane * 16;
      int row = L >> 7;                                 // 0..127
      int off = (L & 127) ^ ((row & 7) << 4);           // pre-swizzled source
      gload16((const char*)A + ((((size_t)(m0 + row)) << 9) + kt) * 2 + off, (char*)As + Lb);
      gload16((const char*)W + ((((size_t)(n0 + row)) << 9) + kt) * 2 + off, (char*)Bs + Lb);
    }
    __syncthreads();
#pragma unroll
    for (int kk = 0; kk < 2; ++kk) {
      bf16x8 af[4], bfr[4];
#pragma unroll
      for (int rt = 0; rt < 4; ++rt) {
        int row = wrow + (rt << 4) + c;
        af[rt] = *(const bf16x8*)((const char*)As + row * 128 + (((kk << 6) | (g << 4)) ^ ((row & 7) << 4)));
      }
#pragma unroll
      for (int ct = 0; ct < 4; ++ct) {
        int row = wcol + (ct << 4) + c;
        bfr[ct] = *(const bf16x8*)((const char*)Bs + row * 128 + (((kk << 6) | (g << 4)) ^ ((row & 7) << 4)));
      }
#pragma unroll
      for (int rt = 0; rt < 4; ++rt)
#pragma unroll
        for (int ct = 0; ct < 4; ++ct) acc[rt][ct] = MFMA16(af[rt], bfr[ct], acc[rt][ct]);
    }
  }

#pragma unroll
  for (int rt = 0; rt < 4; ++rt)
#pragma unroll
    for (int ct = 0; ct < 4; ++ct) {
      int n = n0 + wcol + (ct << 4) + c;
      float bv2 = bias[n];
      if (seg == 2) {
        int b2 = m0 >> 10;
        int sbase = (m0 & 1023) + wrow + (rt << 4) + (g << 2);
        int h2 = n >> 6, d2 = n & 63;
        uint2 o;
        o.x = cvtpk(acc[rt][ct][0] + bv2, acc[rt][ct][1] + bv2);
        o.y = cvtpk(acc[rt][ct][2] + bv2, acc[rt][ct][3] + bv2);
        *(uint2*)(Vt + ((((size_t)((b2 << 3) + h2) << 6) + d2) << 10) + sbase) = o;
      } else {
        u16* out = seg == 0 ? Qh : Kh;
#pragma unroll
        for (int r = 0; r < 4; ++r) {
          int m = m0 + wrow + (rt << 4) + (g << 2) + r;
          int b = m >> 10, s = m & 1023, h = n >> 6, d = n & 63;
          out[(((((size_t)(b * H_ + h)) << 10) + s) << 6) + d] = f2bf(acc[rt][ct][r] + bv2);
        }
      }
    }
}

// ---------------- output GEMM: C fp32 [M][512] = A(bf16) @ W(bf16)^T + bias ----------------
__global__ void __launch_bounds__(256) gemm_out(const u16* __restrict__ A, const u16* __restrict__ W,
                                                const float* __restrict__ bias, float* __restrict__ out) {
  __shared__ u16 As[128 * 64];
  __shared__ u16 Bs[128 * 64];
  const int tid = threadIdx.x, lane = tid & 63, wid = tid >> 6;
  const int c = lane & 15, g = lane >> 4;
  const int bm = blockIdx.x >> 2, bn = blockIdx.x & 3;
  const int m0 = bm << 7, n0 = bn << 7;
  const int wrow = (wid >> 1) << 6, wcol = (wid & 1) << 6;

  const f32x4 ZF = {0.f, 0.f, 0.f, 0.f};
  f32x4 acc[4][4];
#pragma unroll
  for (int i = 0; i < 4; ++i)
#pragma unroll
    for (int j = 0; j < 4; ++j) acc[i][j] = ZF;

  for (int kt = 0; kt < 512; kt += 64) {
    __syncthreads();
#pragma unroll
    for (int i = 0; i < 4; ++i) {
      int Lb = ((wid << 2) | i) << 10;
      int L = Lb + lane * 16;
      int row = L >> 7;
      int off = (L & 127) ^ ((row & 7) << 4);
      gload16((const char*)A + ((((size_t)(m0 + row)) << 9) + kt) * 2 + off, (char*)As + Lb);
      gload16((const char*)W + ((((size_t)(n0 + row)) << 9) + kt) * 2 + off, (char*)Bs + Lb);
    }
    __syncthreads();
#pragma unroll
    for (int kk = 0; kk < 2; ++kk) {
      bf16x8 af[4], bfr[4];
#pragma unroll
      for (int rt = 0; rt < 4; ++rt) {
        int row = wrow + (rt << 4) + c;
        af[rt] = *(const bf16x8*)((const char*)As + row * 128 + (((kk << 6) | (g << 4)) ^ ((row & 7) << 4)));
      }
#pragma unroll
      for (int ct = 0; ct < 4; ++ct) {
        int row = wcol + (ct << 4) + c;
        bfr[ct] = *(const bf16x8*)((const char*)Bs + row * 128 + (((kk << 6) | (g << 4)) ^ ((row & 7) << 4)));
      }
#pragma unroll
      for (int rt = 0; rt < 4; ++rt)
#pragma unroll
        for (int ct = 0; ct < 4; ++ct) acc[rt][ct] = MFMA16(af[rt], bfr[ct], acc[rt][ct]);
    }
  }

#pragma unroll
  for (int rt = 0; rt < 4; ++rt)
#pragma unroll
    for (int ct = 0; ct < 4; ++ct) {
      int n = n0 + wcol + (ct << 4) + c;
      float bv = bias[n];
#pragma unroll
      for (int r = 0; r < 4; ++r) {
        int m = m0 + wrow + (rt << 4) + (g << 2) + r;
        out[(((size_t)m) << 9) + n] = acc[rt][ct][r] + bv;
      }
    }
}

// ---------------- flash attention: 8 waves, 128 q-rows/block, fused qrel + rel-V ----------------
// lane (c,g) of wave wid owns q = qbase + wid*16 + c everywhere.
__global__ void __launch_bounds__(512) flash_kernel(const u16* __restrict__ Qh, const u16* __restrict__ Kh,
                                                    const u16* __restrict__ Vt, const u16* __restrict__ relkb,
                                                    const float* __restrict__ relv, u16* __restrict__ Xout) {
  __shared__ u16 Ks[2][64 * 64];
  __shared__ u16 Vs[2][64 * 64];
  __shared__ u16 Ps[128 * 64];
  __shared__ float qrelS[128 * 34];   // exp2-domain bias table; overlaid by rvT in epilogue
  __shared__ u16 Pband[128 * 32];     // unnormalized bf16 band probs; slot 0 = low bucket
  __shared__ float rv32S[64];

  const int tid = threadIdx.x, lane = tid & 63, wid = tid >> 6;
  const int c = lane & 15, g = lane >> 4;
  // XCD swizzle: 8 chunks of 64 consecutive blocks
  const int swz = ((blockIdx.x & 7) << 6) | (blockIdx.x >> 3);
  const int bh = swz >> 3, qt = swz & 7;
  const int qbase = qt << 7;
  const size_t rowbase = ((size_t)bh) << 10;
  const int qloc = (wid << 4) + c;
  const float K1 = 0.51013619f;   // (1/sqrt(8)) * log2(e)
  const float C0 = 24.0f;

  // Q fragments (issue loads first)
  bf16x8 qa[2];
  {
    const u16* qptr = Qh + ((rowbase + qbase + qloc) << 6);
    qa[0] = *(const bf16x8*)(qptr + (g << 3));
    qa[1] = *(const bf16x8*)(qptr + 32 + (g << 3));
  }

#define STAGE(buf, kt_) do { \
    const int k64_ = (kt_) << 6; \
    int L_ = (wid << 10) + lane * 16; \
    int row_ = L_ >> 7; \
    int off_ = (L_ & 127) ^ ((row_ & 7) << 4); \
    gload16((const char*)Kh + ((rowbase + k64_ + row_) << 7) + off_, (char*)Ks[buf] + (wid << 10)); \
    gload16((const char*)Vt + ((((size_t)bh << 6) + row_) << 11) + (k64_ << 1) + off_, (char*)Vs[buf] + (wid << 10)); \
  } while (0)

  STAGE(0, 0);

  // zero Pband (8192B), load rv32
  ((uint4*)Pband)[tid] = uint4{0, 0, 0, 0};
  if (tid < 64) rv32S[tid] = relv[2048 + tid];

  // qrel in prologue: qrelS[q][r] = (Q[q,:].relk[r,:]) * K1 - C0, via 6 MFMAs per wave
  {
    const f32x4 ZF = {0.f, 0.f, 0.f, 0.f};
#pragma unroll
    for (int t = 0; t < 3; ++t) {
      int rr = t * 16 + c; if (rr > 32) rr = 32;
      f32x4 qr = ZF;
#pragma unroll
      for (int kk = 0; kk < 2; ++kk) {
        bf16x8 ar = *(const bf16x8*)(relkb + (rr << 6) + (kk << 5) + (g << 3));
        qr = MFMA16(ar, qa[kk], qr);
      }
#pragma unroll
      for (int j = 0; j < 4; ++j) {
        int r = t * 16 + (g << 2) + j;
        if (r < 33) qrelS[qloc * 34 + r] = qr[j] * K1 - C0;
      }
    }
  }
  __syncthreads();   // covers STAGE(0), Pband init, qrelS, rv32S

  const float bias_lo = qrelS[qloc * 34 + 0];
  const float bias_hi = qrelS[qloc * 34 + 32];

  // hoisted loop-invariant LDS byte offsets
  int koff[4][2], voff[4][2], poffw[4];
#pragma unroll
  for (int t = 0; t < 4; ++t) {
#pragma unroll
    for (int kk = 0; kk < 2; ++kk)
      koff[t][kk] = ((t << 4) + c) * 128 + ((((kk << 6) | (g << 4))) ^ ((c & 7) << 4));
#pragma unroll
    for (int h2 = 0; h2 < 2; ++h2)
      voff[t][h2] = ((t << 4) + c) * 128 + ((((h2 << 6) | (g << 4))) ^ ((c & 7) << 4));
    poffw[t] = qloc * 128 + (((t << 5) | (g << 3)) ^ ((c & 7) << 4));
  }
  const int pr0 = qloc * 128 + ((g << 4) ^ ((c & 7) << 4));
  const int pr1 = pr0 ^ 64;

  const f32x4 ZF = {0.f, 0.f, 0.f, 0.f};
  f32x4 acc[4] = {ZF, ZF, ZF, ZF};
  float lsum = 0.f, lowsum = 0.f, psum = 0.f;

  for (int kt = 0; kt < 16; ++kt) {
    const int cur = kt & 1;
    if (kt < 15) STAGE(cur ^ 1, kt + 1);   // prefetch into other buffer

    // QK^T swapped: sa[t][j] = S[k = kt*64 + t*16 + g*4 + j][q = own]
    f32x4 sa[4];
#pragma unroll
    for (int t = 0; t < 4; ++t) {
      sa[t] = ZF;
#pragma unroll
      for (int kk = 0; kk < 2; ++kk) {
        bf16x8 bk = *(const bf16x8*)((const char*)Ks + (cur << 13) + koff[t][kk]);
        sa[t] = MFMA16(bk, qa[kk], sa[t]);
      }
    }

    const int D0 = (kt << 6) - qbase;
    float p[4][4];
    if (D0 >= 192) {            // all dlt >= 17: high bucket
      float s = 0.f;
#pragma unroll
      for (int t = 0; t < 4; ++t)
#pragma unroll
        for (int j = 0; j < 4; ++j) {
          float pe = __builtin_amdgcn_exp2f(fmaf(sa[t][j], K1, bias_hi));
          p[t][j] = pe; s += pe;
        }
      lsum += s;
    } else if (D0 <= -128) {    // all dlt <= -17: low bucket
      float s = 0.f;
#pragma unroll
      for (int t = 0; t < 4; ++t)
#pragma unroll
        for (int j = 0; j < 4; ++j) {
          float pe = __builtin_amdgcn_exp2f(fmaf(sa[t][j], K1, bias_lo));
          p[t][j] = pe; s += pe;
        }
      lsum += s; lowsum += s;
    } else {                    // boundary tiles (4 of 16)
#pragma unroll
      for (int t = 0; t < 4; ++t)
#pragma unroll
        for (int j = 0; j < 4; ++j) {
          int dlt = D0 + (t << 4) + (g << 2) + j - qloc;
          int idx = dlt < -16 ? 0 : (dlt > 16 ? 32 : dlt + 16);
          float pe = __builtin_amdgcn_exp2f(fmaf(sa[t][j], K1, qrelS[qloc * 34 + idx]));
          p[t][j] = pe;
          lsum += pe;
          if (dlt <= -16) lowsum += pe;
          else if (dlt < 16) { psum += pe; Pband[(qloc << 5) + dlt + 16] = f2bf(pe); }
        }
    }

    // P -> LDS (own row), then PV swapped: acc[dt][j] = O[d = dt*16+g*4+j][q = own]
#pragma unroll
    for (int t = 0; t < 4; ++t) {
      uint2 pk;
      pk.x = cvtpk(p[t][0], p[t][1]);
      pk.y = cvtpk(p[t][2], p[t][3]);
      *(uint2*)((char*)Ps + poffw[t]) = pk;
    }
    bf16x8 pb0 = *(const bf16x8*)((const char*)Ps + pr0);
    bf16x8 pb1 = *(const bf16x8*)((const char*)Ps + pr1);
#pragma unroll
    for (int dt = 0; dt < 4; ++dt) {
      bf16x8 av0 = *(const bf16x8*)((const char*)Vs + (cur << 13) + voff[dt][0]);
      bf16x8 av1 = *(const bf16x8*)((const char*)Vs + (cur << 13) + voff[dt][1]);
      acc[dt] = MFMA16(av0, pb0, acc[dt]);
      acc[dt] = MFMA16(av1, pb1, acc[dt]);
    }
    __syncthreads();   // drains prefetch + protects dbuf swap
  }

  // ---- epilogue ----
  lsum += __shfl_xor(lsum, 16);   lsum += __shfl_xor(lsum, 32);
  lowsum += __shfl_xor(lowsum, 16); lowsum += __shfl_xor(lowsum, 32);
  psum += __shfl_xor(psum, 16);   psum += __shfl_xor(psum, 32);
  const float inv = 1.f / lsum;
  const float hsum = lsum - lowsum - psum;   // unnormalized high-bucket mass

  if (g == 0) Pband[qloc << 5] = f2bf(lowsum);   // low bucket slot (unnormalized)

  // overlay rv^T (bf16 [d][r=0..31]) into dead qrelS
  u16* rvT = (u16*)qrelS;
  for (int i = tid; i < 4096; i += 512) rvT[i] = f2bf(relv[((i & 31) << 6) + (i >> 5)]);
  __syncthreads();

  // acc += rv^T[d][r] * Pband[r][q]  (band + low), all unnormalized
  bf16x8 pb2 = *(const bf16x8*)((const u16*)Pband + (qloc << 5) + (g << 3));
#pragma unroll
  for (int dt = 0; dt < 4; ++dt) {
    bf16x8 av = *(const bf16x8*)(rvT + (((dt << 4) + c) << 5) + (g << 3));
    acc[dt] = MFMA16(av, pb2, acc[dt]);
  }

  const int b = bh >> 3, h = bh & 7;
  const int q = qbase + qloc;
  u16* xb = Xout + ((((size_t)b << 10) + q) << 9) + (h << 6);
#pragma unroll
  for (int dt = 0; dt < 4; ++dt) {
    int d0 = (dt << 4) + (g << 2);
    float v0 = (acc[dt][0] + hsum * rv32S[d0 + 0]) * inv;
    float v1 = (acc[dt][1] + hsum * rv32S[d0 + 1]) * inv;
    float v2 = (acc[dt][2] + hsum * rv32S[d0 + 2]) * inv;
    float v3 = (acc[dt][3] + hsum * rv32S[d0 + 3]) * inv;
    uint2 o;
    o.x = cvtpk(v0, v1);
    o.y = cvtpk(v2, v3);
    *(uint2*)(xb + d0) = o;
  }
#undef STAGE
}

// ---------------- launch ----------------
extern "C" void kernel_launch(void* const* d_in, const int* in_sizes, int n_in,
                              void* d_out, int out_size, void* d_ws, size_t ws_size,
                              hipStream_t stream) {
  (void)in_sizes; (void)n_in; (void)out_size; (void)ws_size;
  const float* query = (const float*)d_in[0];
  const float* key   = (const float*)d_in[1];
  const float* value = (const float*)d_in[2];
  const float* Wq = (const float*)d_in[3];
  const float* bq = (const float*)d_in[4];
  const float* Wk = (const float*)d_in[5];
  const float* bk = (const float*)d_in[6];
  const float* Wv = (const float*)d_in[7];
  const float* bv = (const float*)d_in[8];
  const float* Wo = (const float*)d_in[9];
  const float* bo = (const float*)d_in[10];
  const float* relk = (const float*)d_in[11];
  const float* relv = (const float*)d_in[12];

  char* ws = (char*)d_ws;
  u16*   Xq    = (u16*)(ws + 0);
  u16*   Xk    = (u16*)(ws + 8388608);
  u16*   Xv    = (u16*)(ws + 16777216);
  u16*   Wqb   = (u16*)(ws + 25165824);
  u16*   Wkb   = (u16*)(ws + 25690112);
  u16*   Wvb   = (u16*)(ws + 26214400);
  u16*   Wob   = (u16*)(ws + 26738688);
  u16*   relkb = (u16*)(ws + 27262976);   // 33*64 bf16
  u16*   Qh    = (u16*)(ws + 27271168);
  u16*   Kh    = (u16*)(ws + 35659776);
  u16*   Vt    = (u16*)(ws + 52436992);
  u16*   Xout  = (u16*)(ws + 70262784);

  convAll<<<13315, 256, 0, stream>>>(query, key, value, Wq, Wk, Wv, Wo, relk,
                                     Xq, Xk, Xv, Wqb, Wkb, Wvb, Wob, relkb);
  qkv_gemm<<<768, 256, 0, stream>>>(Xq, Xk, Xv, Wqb, Wkb, Wvb, bq, bk, bv, Qh, Kh, Vt);
  flash_kernel<<<512, 512, 0, stream>>>(Qh, Kh, Vt, relkb, relv, Xout);
  gemm_out<<<256, 256, 0, stream>>>(Xout, Wob, bo, (float*)d_out);
}